// Round 9
// baseline (154.330 us; speedup 1.0000x reference)
//
#include <hip/hip_runtime.h>

#define D 64
#define BIN_SHIFT 7
#define BIN_SIZE 128
#define MAX_BINS 1024
#define BINCAP 2560              // bin load ~ Poisson(1600), sigma 40 -> +24 sigma
#define K1_THREADS 1024
#define K1_EPT 5
#define K1_EPB (K1_THREADS * K1_EPT)   // 5120 edges/block -> 245 sort blocks
#define K2_THREADS 512
#define NREL 32

// rec packing: tail[16:0] | rel[21:17] | head_local[28:22]

typedef __attribute__((address_space(3))) unsigned char lds_u8_t;
typedef __attribute__((address_space(1))) const unsigned char gbl_u8_t;

__device__ __forceinline__ float bf2f(unsigned short u) {
    union { unsigned i; float f; } x; x.i = ((unsigned)u) << 16; return x.f;
}

// ---------- K1+K0 fused: sort blocks [0,nsort), cvt blocks [nsort, ...) ------
__global__ void __launch_bounds__(K1_THREADS)
prep_kernel(const float* __restrict__ emb,
            unsigned short* __restrict__ emb16,
            const int* __restrict__ head,
            const int* __restrict__ tail,
            const int* __restrict__ etype,
            int* __restrict__ binCount,     // [nbins] global cursors (pre-zeroed)
            unsigned* __restrict__ recs,    // [nbins * BINCAP]
            int nbins, int n_edges, long n4, int nsort) {
    __shared__ unsigned srec[K1_EPB];       // 20KB: block's recs sorted by bin
    __shared__ int hist[MAX_BINS];          // 4KB
    __shared__ int base[MAX_BINS + 1];      // 4KB
    __shared__ int cur[MAX_BINS];           // 4KB
    __shared__ int gpos[MAX_BINS];          // 4KB
    __shared__ unsigned short binof[K1_EPB];// 10KB: slot -> bin (O(1) lookup)
    __shared__ int wtot[16];
    __shared__ int wexcl[16];

    int tid = threadIdx.x;

    if (blockIdx.x >= nsort) {              // ---- cvt section (block-uniform)
        long i = (long)(blockIdx.x - nsort) * K1_THREADS + tid;
        if (i >= n4) return;
        float4 v = ((const float4*)emb)[i];
        ushort4 o;
        unsigned b;
        b = __float_as_uint(v.x); o.x = (unsigned short)((b + 0x7FFF + ((b >> 16) & 1)) >> 16);
        b = __float_as_uint(v.y); o.y = (unsigned short)((b + 0x7FFF + ((b >> 16) & 1)) >> 16);
        b = __float_as_uint(v.z); o.z = (unsigned short)((b + 0x7FFF + ((b >> 16) & 1)) >> 16);
        b = __float_as_uint(v.w); o.w = (unsigned short)((b + 0x7FFF + ((b >> 16) & 1)) >> 16);
        ((ushort4*)emb16)[i] = o;
        return;
    }

    // ---- sort section -------------------------------------------------------
    hist[tid] = 0;                          // 1024 threads = MAX_BINS exactly
    __syncthreads();

    long blockBase = (long)blockIdx.x * K1_EPB;
    int nvalid = (int)(((long)n_edges - blockBase < (long)K1_EPB)
                       ? ((long)n_edges - blockBase) : (long)K1_EPB);

    unsigned rv[K1_EPT]; int bv[K1_EPT];
#pragma unroll
    for (int k = 0; k < K1_EPT; k++) {                 // coalesced edge reads
        long e = blockBase + (long)k * K1_THREADS + tid;
        if (e < n_edges) {
            int h = head[e];
            bv[k] = h >> BIN_SHIFT;
            rv[k] = (unsigned)tail[e] | ((unsigned)etype[e] << 17)
                  | ((unsigned)(h & (BIN_SIZE - 1)) << 22);
            atomicAdd(&hist[bv[k]], 1);
        } else bv[k] = -1;
    }
    __syncthreads();

    // exclusive scan of hist[1024]: one thread per bin, shfl hierarchical
    int lane = tid & 63, wv = tid >> 6;
    int h0 = hist[tid];
    int v = h0;
#pragma unroll
    for (int s = 1; s < 64; s <<= 1) {
        int x = __shfl_up(v, s);
        if (lane >= s) v += x;
    }
    if (lane == 63) wtot[wv] = v;
    __syncthreads();
    if (wv == 0 && lane < 16) {
        int t = wtot[lane];
        int a = t;
#pragma unroll
        for (int s = 1; s < 16; s <<= 1) {
            int x = __shfl_up(a, s);
            if (lane >= s) a += x;
        }
        wexcl[lane] = a - t;
    }
    __syncthreads();
    int incl = v + wexcl[wv];
    base[tid] = incl - h0;  cur[tid] = incl - h0;
    if (tid == K1_THREADS - 1) base[MAX_BINS] = incl;
    __syncthreads();

    // reserve one contiguous global run per (block, bin)
    if (tid < nbins) {
        int c = hist[tid];
        gpos[tid] = (c > 0) ? atomicAdd(&binCount[tid], c) : 0;
    }
    __syncthreads();

    // LDS scatter into bin-sorted order
#pragma unroll
    for (int k = 0; k < K1_EPT; k++) {
        if (bv[k] >= 0) {
            int p = atomicAdd(&cur[bv[k]], 1);
            srec[p] = rv[k];
        }
    }
    __syncthreads();

    // O(n) slot->bin table
    if (tid < nbins) {
        int j0 = base[tid], j1 = base[tid + 1];
        for (int j = j0; j < j1; j++) binof[j] = (unsigned short)tid;
    }
    __syncthreads();

    // copy runs out: consecutive i -> consecutive global dst within a run
    for (int i = tid; i < nvalid; i += K1_THREADS) {
        int b = binof[i];
        int off = gpos[b] + (i - base[b]);
        if (off < BINCAP)
            recs[(long)b * BINCAP + off] = srec[i];
    }
}

// ---------- K2: per-bin LDS sort + LDS-staged deep-pipelined gather ----------
// global_load_lds stages head j+1/j+2's 16 rows (2KB) into a per-wave 2-slot
// LDS ring: loads are fire-and-forget (no VGPR cost), depth-2 per wave,
// synced by hand-counted s_waitcnt vmcnt(2) (per-wave, no barriers in loop).
__global__ void __launch_bounds__(K2_THREADS, 2)
aggregate_bin_kernel(const unsigned short* __restrict__ emb16,
                     const float* __restrict__ weight,
                     const unsigned* __restrict__ recs,
                     const int* __restrict__ binCount,
                     float* __restrict__ out, int n_ent) {
    __shared__ unsigned stage_raw[8192];       // 32KB: setup=raw recs, main=stage ring
    __shared__ unsigned sorted[BINCAP + 16];   // +16: zeroed pad for over-reads
    __shared__ float wlds[NREL * D];           // 8KB relation-weight cache
    __shared__ float wz[D];                    // 256B zero weights (pad lanes)
    __shared__ int hist[BIN_SIZE];
    __shared__ int off[BIN_SIZE];
    __shared__ int cur[BIN_SIZE];

    unsigned* raw = stage_raw;                 // alias: raw[] only live pre-sort

    int tid = threadIdx.x;
    int b = blockIdx.x;
    int n = min(binCount[b], BINCAP);

    // zero only the 16-entry pad [n, n+16) — scatter fills [0,n)
    if (tid < 16) sorted[n + tid] = 0u;
    if (tid >= 448 && tid < 448 + D) wz[tid - 448] = 0.f;
    for (int i = tid; i < NREL * D; i += K2_THREADS) wlds[i] = weight[i];
    if (tid < BIN_SIZE) hist[tid] = 0;
    __syncthreads();

    const unsigned* gr = recs + (long)b * BINCAP;
    for (int i = tid; i < n; i += K2_THREADS) {   // contiguous ~10KB read
        unsigned q = gr[i];
        raw[i] = q;
        atomicAdd(&hist[(q >> 22) & 127], 1);
    }
    __syncthreads();

    int lane = tid & 63;
    int wave = tid >> 6;

    // single-wave shfl exclusive scan of hist[128]
    if (wave == 0) {
        int h0 = hist[lane];
        int h1 = hist[64 + lane];
        int s0 = h0, s1 = h1;
#pragma unroll
        for (int s = 1; s < 64; s <<= 1) {
            int t0 = __shfl_up(s0, s);
            int t1 = __shfl_up(s1, s);
            if (lane >= s) { s0 += t0; s1 += t1; }
        }
        int tot0 = __shfl(s0, 63);
        int e0 = s0 - h0;
        int e1 = tot0 + s1 - h1;
        off[lane] = e0;      cur[lane] = e0;
        off[64 + lane] = e1; cur[64 + lane] = e1;
    }
    __syncthreads();

    for (int i = tid; i < n; i += K2_THREADS) {   // LDS scatter into sorted order
        unsigned q = raw[i];
        int p = atomicAdd(&cur[(q >> 22) & 127], 1);
        sorted[p] = q;
    }
    __syncthreads();                              // raw[] dead; stage ring live

    int g = lane >> 4;            // edge subgroup (0..3)
    int c4 = (lane & 15) << 2;    // feature quad offset (ushort units)
    int r8 = lane >> 3;           // stage: row within 8-row group (0..7)
    int ch8 = lane & 7;           // stage: 16B chunk within row (0..7)
    int hbase = b << BIN_SHIFT;
    char* mySlot = (char*)stage_raw + wave * 4096;   // 2 slots x 2KB per wave

// stage head J's first 16 rows into LDS slot: 2 x global_load_lds (8 rows each)
#define K2_STAGE(J, SLOT)                                                      \
    do {                                                                       \
        int hh_ = wave + ((J) << 3);                                           \
        int o_ = off[hh_], d_ = hist[hh_];                                     \
        int ea_ = r8, eb_ = 8 + r8;                                            \
        unsigned qa_ = (ea_ < d_) ? sorted[o_ + ea_] : 0u;                     \
        unsigned qb_ = (eb_ < d_) ? sorted[o_ + eb_] : 0u;                     \
        const unsigned short* ga_ =                                            \
            &emb16[((long)(qa_ & 0x1FFFF) << 6) + (ch8 << 3)];                 \
        const unsigned short* gb_ =                                            \
            &emb16[((long)(qb_ & 0x1FFFF) << 6) + (ch8 << 3)];                 \
        char* l0_ = mySlot + (SLOT) * 2048;                                    \
        __builtin_amdgcn_global_load_lds((gbl_u8_t*)ga_, (lds_u8_t*)l0_,       \
                                         16, 0, 0);                            \
        __builtin_amdgcn_global_load_lds((gbl_u8_t*)gb_,                       \
                                         (lds_u8_t*)(l0_ + 1024), 16, 0, 0);   \
    } while (0)

#define K2_COMP(J, SLOT)                                                       \
    do {                                                                       \
        int hh_ = wave + ((J) << 3);                                           \
        int o_ = off[hh_], d_ = hist[hh_];                                     \
        const unsigned short* S_ =                                             \
            (const unsigned short*)(mySlot + (SLOT) * 2048);                   \
        float4 acc = make_float4(0.f, 0.f, 0.f, 0.f);                          \
        int e0 = g, e1 = 4 + g, e2 = 8 + g, e3 = 12 + g;                       \
        unsigned q0 = sorted[o_ + e0]; unsigned q1 = sorted[o_ + e1];          \
        unsigned q2 = sorted[o_ + e2]; unsigned q3 = sorted[o_ + e3];          \
        bool k0 = (e0 < d_), k1 = (e1 < d_), k2 = (e2 < d_), k3 = (e3 < d_);   \
        ushort4 u0 = *(const ushort4*)&S_[(e0 << 6) + c4];                     \
        ushort4 u1 = *(const ushort4*)&S_[(e1 << 6) + c4];                     \
        ushort4 u2 = *(const ushort4*)&S_[(e2 << 6) + c4];                     \
        ushort4 u3 = *(const ushort4*)&S_[(e3 << 6) + c4];                     \
        float4 w0 = *(const float4*)(k0 ? &wlds[(((q0 >> 17) & 31) << 6) + c4] \
                                        : &wz[c4]);                            \
        float4 w1 = *(const float4*)(k1 ? &wlds[(((q1 >> 17) & 31) << 6) + c4] \
                                        : &wz[c4]);                            \
        float4 w2 = *(const float4*)(k2 ? &wlds[(((q2 >> 17) & 31) << 6) + c4] \
                                        : &wz[c4]);                            \
        float4 w3 = *(const float4*)(k3 ? &wlds[(((q3 >> 17) & 31) << 6) + c4] \
                                        : &wz[c4]);                            \
        acc.x += bf2f(u0.x) * w0.x; acc.y += bf2f(u0.y) * w0.y;                \
        acc.z += bf2f(u0.z) * w0.z; acc.w += bf2f(u0.w) * w0.w;                \
        acc.x += bf2f(u1.x) * w1.x; acc.y += bf2f(u1.y) * w1.y;                \
        acc.z += bf2f(u1.z) * w1.z; acc.w += bf2f(u1.w) * w1.w;                \
        acc.x += bf2f(u2.x) * w2.x; acc.y += bf2f(u2.y) * w2.y;                \
        acc.z += bf2f(u2.z) * w2.z; acc.w += bf2f(u2.w) * w2.w;                \
        acc.x += bf2f(u3.x) * w3.x; acc.y += bf2f(u3.y) * w3.y;                \
        acc.z += bf2f(u3.z) * w3.z; acc.w += bf2f(u3.w) * w3.w;                \
        for (int i_ = 16; i_ < d_; i_ += 16) {  /* deg>16 tail: global path */ \
            int e0_ = i_ + g, e1_ = i_ + 4 + g, e2_ = i_ + 8 + g,              \
                e3_ = i_ + 12 + g;                                             \
            unsigned t0 = sorted[o_ + e0_]; unsigned t1 = sorted[o_ + e1_];    \
            unsigned t2 = sorted[o_ + e2_]; unsigned t3 = sorted[o_ + e3_];    \
            bool c0 = (e0_ < d_), c1 = (e1_ < d_), c2 = (e2_ < d_),            \
                 c3 = (e3_ < d_);                                              \
            t0 = c0 ? t0 : 0u;  t1 = c1 ? t1 : 0u;                             \
            t2 = c2 ? t2 : 0u;  t3 = c3 ? t3 : 0u;                             \
            ushort4 v0 = *(const ushort4*)&emb16[((long)(t0 & 0x1FFFF) << 6) + c4]; \
            ushort4 v1 = *(const ushort4*)&emb16[((long)(t1 & 0x1FFFF) << 6) + c4]; \
            ushort4 v2 = *(const ushort4*)&emb16[((long)(t2 & 0x1FFFF) << 6) + c4]; \
            ushort4 v3 = *(const ushort4*)&emb16[((long)(t3 & 0x1FFFF) << 6) + c4]; \
            float4 x0 = *(const float4*)(c0 ? &wlds[(((t0 >> 17) & 31) << 6) + c4] \
                                            : &wz[c4]);                        \
            float4 x1 = *(const float4*)(c1 ? &wlds[(((t1 >> 17) & 31) << 6) + c4] \
                                            : &wz[c4]);                        \
            float4 x2 = *(const float4*)(c2 ? &wlds[(((t2 >> 17) & 31) << 6) + c4] \
                                            : &wz[c4]);                        \
            float4 x3 = *(const float4*)(c3 ? &wlds[(((t3 >> 17) & 31) << 6) + c4] \
                                            : &wz[c4]);                        \
            acc.x += bf2f(v0.x) * x0.x; acc.y += bf2f(v0.y) * x0.y;            \
            acc.z += bf2f(v0.z) * x0.z; acc.w += bf2f(v0.w) * x0.w;            \
            acc.x += bf2f(v1.x) * x1.x; acc.y += bf2f(v1.y) * x1.y;            \
            acc.z += bf2f(v1.z) * x1.z; acc.w += bf2f(v1.w) * x1.w;            \
            acc.x += bf2f(v2.x) * x2.x; acc.y += bf2f(v2.y) * x2.y;            \
            acc.z += bf2f(v2.z) * x2.z; acc.w += bf2f(v2.w) * x2.w;            \
            acc.x += bf2f(v3.x) * x3.x; acc.y += bf2f(v3.y) * x3.y;            \
            acc.z += bf2f(v3.z) * x3.z; acc.w += bf2f(v3.w) * x3.w;            \
        }                                                                      \
        acc.x += __shfl_xor(acc.x, 16); acc.y += __shfl_xor(acc.y, 16);        \
        acc.z += __shfl_xor(acc.z, 16); acc.w += __shfl_xor(acc.w, 16);        \
        acc.x += __shfl_xor(acc.x, 32); acc.y += __shfl_xor(acc.y, 32);        \
        acc.z += __shfl_xor(acc.z, 32); acc.w += __shfl_xor(acc.w, 32);        \
        if (g == 0 && hbase + hh_ < n_ent) {                                   \
            float inv = 1.f / fmaxf((float)d_, 1.f);                           \
            *(float4*)&out[((long)(hbase + hh_) << 6) + c4] =                  \
                make_float4(acc.x * inv, acc.y * inv, acc.z * inv, acc.w * inv);\
        }                                                                      \
    } while (0)

    K2_STAGE(0, 0);
    K2_STAGE(1, 1);
#pragma unroll 1
    for (int j = 0; j < 16; ++j) {
        // wait until only slot (j+1)'s 2 stages may remain outstanding
        asm volatile("s_waitcnt vmcnt(2)" ::: "memory");
        K2_COMP(j, j & 1);
        if (j < 14) K2_STAGE(j + 2, j & 1);   // slot j&1 consumed; safe reuse
    }
#undef K2_STAGE
#undef K2_COMP
}

// ---------- Fallback (R1 atomic version) for out-of-envelope shapes ----------
__global__ void fb_scatter(const float* __restrict__ emb, const int* __restrict__ head,
                           const int* __restrict__ tail, const int* __restrict__ etype,
                           const float* __restrict__ weight, float* __restrict__ out,
                           float* __restrict__ cnt, int n_edges) {
    int gtid = blockIdx.x * blockDim.x + threadIdx.x;
    int e = gtid >> 6, lane = threadIdx.x & 63;
    if (e >= n_edges) return;
    int h = head[e], t = tail[e], r = etype[e];
    atomicAdd(&out[(long)h * D + lane], emb[(long)t * D + lane] * weight[r * D + lane]);
    if (lane == 0) atomicAdd(&cnt[h], 1.0f);
}
__global__ void fb_divide(float* __restrict__ out, const float* __restrict__ cnt, int n) {
    int i = blockIdx.x * blockDim.x + threadIdx.x;
    if (i < n) out[i] = out[i] / fmaxf(cnt[i >> 6], 1.0f);
}

// ===========================================================================

extern "C" void kernel_launch(void* const* d_in, const int* in_sizes, int n_in,
                              void* d_out, int out_size, void* d_ws, size_t ws_size,
                              hipStream_t stream) {
    const float* emb    = (const float*)d_in[0];  // [N_ENT, 64] fp32
    const int*   eidx   = (const int*)  d_in[1];  // [2, E] int32
    const int*   etype  = (const int*)  d_in[2];  // [E] int32
    const float* weight = (const float*)d_in[3];  // [32, 64] fp32
    float* out = (float*)d_out;

    int n_edges = in_sizes[2];
    int n_ent   = out_size / D;
    const int* head = eidx;
    const int* tail = eidx + n_edges;

    int nbins = (n_ent + BIN_SIZE - 1) >> BIN_SHIFT;           // 782 for 100k
    size_t recs_bytes = sizeof(int) * ((size_t)nbins * BINCAP);
    size_t cnt_bytes  = sizeof(int) * (size_t)nbins;
    size_t emb16_off  = (cnt_bytes + recs_bytes + 15) & ~((size_t)15);
    size_t need = emb16_off + (size_t)n_ent * D * sizeof(unsigned short);
    long mean_load = (n_ent > 0) ? ((long)n_edges * BIN_SIZE / n_ent) : 0;   // 1600
    bool ok = (n_ent <= 131072) && (nbins <= MAX_BINS) && (ws_size >= need) &&
              (mean_load + 700 <= BINCAP);

    if (ok) {
        int* binCount  = (int*)d_ws;                     // [nbins]
        unsigned* recs = (unsigned*)(binCount + nbins);  // [nbins * BINCAP]
        unsigned short* emb16 = (unsigned short*)((char*)d_ws + emb16_off);

        long n4 = (long)n_ent * D / 4;                   // float4 count (D=64 -> exact)
        int nsort = (n_edges + K1_EPB - 1) / K1_EPB;     // 245 for 1.25M
        int ncvt  = (int)((n4 + K1_THREADS - 1) / K1_THREADS);

        hipMemsetAsync(binCount, 0, (size_t)nbins * sizeof(int), stream);
        prep_kernel<<<nsort + ncvt, K1_THREADS, 0, stream>>>(
            emb, emb16, head, tail, etype, binCount, recs,
            nbins, n_edges, n4, nsort);

        aggregate_bin_kernel<<<nbins, K2_THREADS, 0, stream>>>(
            emb16, weight, recs, binCount, out, n_ent);
    } else {
        float* cnt = (float*)d_ws;
        hipMemsetAsync(out, 0, (size_t)out_size * sizeof(float), stream);
        hipMemsetAsync(cnt, 0, (size_t)n_ent * sizeof(float), stream);
        long tt = (long)n_edges * 64;
        fb_scatter<<<(int)((tt + 255) / 256), 256, 0, stream>>>(
            emb, head, tail, etype, weight, out, cnt, n_edges);
        fb_divide<<<(out_size + 255) / 256, 256, 0, stream>>>(out, cnt, out_size);
    }
}

// Round 11
// 145.177 us; speedup vs baseline: 1.0631x; 1.0631x over previous
//
#include <hip/hip_runtime.h>

#define D 64
#define BIN_SHIFT 7
#define BIN_SIZE 128
#define MAX_BINS 1024
#define BINCAP 2560              // bin load ~ Poisson(1600), sigma 40 -> +24 sigma
#define K1_THREADS 1024
#define K1_EPT 5
#define K1_EPB (K1_THREADS * K1_EPT)   // 5120 edges/block -> 245 sort blocks
#define K2_THREADS 512
#define NREL 32

// rec packing: tail[16:0] | rel[21:17] | head_local[28:22]

__device__ __forceinline__ float bf2f(unsigned short u) {
    union { unsigned i; float f; } x; x.i = ((unsigned)u) << 16; return x.f;
}

// ---------- K1+K0 fused: sort blocks [0,nsort), cvt blocks [nsort, ...) ------
__global__ void __launch_bounds__(K1_THREADS)
prep_kernel(const float* __restrict__ emb,
            unsigned short* __restrict__ emb16,
            const int* __restrict__ head,
            const int* __restrict__ tail,
            const int* __restrict__ etype,
            int* __restrict__ binCount,     // [nbins] global cursors (pre-zeroed)
            unsigned* __restrict__ recs,    // [nbins * BINCAP]
            int nbins, int n_edges, long n4, int nsort) {
    __shared__ unsigned srec[K1_EPB];       // 20KB: block's recs sorted by bin
    __shared__ int hist[MAX_BINS];          // 4KB
    __shared__ int base[MAX_BINS + 1];      // 4KB
    __shared__ int cur[MAX_BINS];           // 4KB
    __shared__ int gpos[MAX_BINS];          // 4KB
    __shared__ unsigned short binof[K1_EPB];// 10KB: slot -> bin (O(1) lookup)
    __shared__ int wtot[16];
    __shared__ int wexcl[16];

    int tid = threadIdx.x;

    if (blockIdx.x >= nsort) {              // ---- cvt section (block-uniform)
        long i = (long)(blockIdx.x - nsort) * K1_THREADS + tid;
        if (i >= n4) return;
        float4 v = ((const float4*)emb)[i];
        ushort4 o;
        unsigned b;
        b = __float_as_uint(v.x); o.x = (unsigned short)((b + 0x7FFF + ((b >> 16) & 1)) >> 16);
        b = __float_as_uint(v.y); o.y = (unsigned short)((b + 0x7FFF + ((b >> 16) & 1)) >> 16);
        b = __float_as_uint(v.z); o.z = (unsigned short)((b + 0x7FFF + ((b >> 16) & 1)) >> 16);
        b = __float_as_uint(v.w); o.w = (unsigned short)((b + 0x7FFF + ((b >> 16) & 1)) >> 16);
        ((ushort4*)emb16)[i] = o;
        return;
    }

    // ---- sort section -------------------------------------------------------
    hist[tid] = 0;                          // 1024 threads = MAX_BINS exactly
    __syncthreads();

    long blockBase = (long)blockIdx.x * K1_EPB;
    int nvalid = (int)(((long)n_edges - blockBase < (long)K1_EPB)
                       ? ((long)n_edges - blockBase) : (long)K1_EPB);

    unsigned rv[K1_EPT]; int bv[K1_EPT];
#pragma unroll
    for (int k = 0; k < K1_EPT; k++) {                 // coalesced edge reads
        long e = blockBase + (long)k * K1_THREADS + tid;
        if (e < n_edges) {
            int h = head[e];
            bv[k] = h >> BIN_SHIFT;
            rv[k] = (unsigned)tail[e] | ((unsigned)etype[e] << 17)
                  | ((unsigned)(h & (BIN_SIZE - 1)) << 22);
            atomicAdd(&hist[bv[k]], 1);
        } else bv[k] = -1;
    }
    __syncthreads();

    // exclusive scan of hist[1024]: one thread per bin, shfl hierarchical
    int lane = tid & 63, wv = tid >> 6;
    int h0 = hist[tid];
    int v = h0;
#pragma unroll
    for (int s = 1; s < 64; s <<= 1) {
        int x = __shfl_up(v, s);
        if (lane >= s) v += x;
    }
    if (lane == 63) wtot[wv] = v;
    __syncthreads();
    if (wv == 0 && lane < 16) {
        int t = wtot[lane];
        int a = t;
#pragma unroll
        for (int s = 1; s < 16; s <<= 1) {
            int x = __shfl_up(a, s);
            if (lane >= s) a += x;
        }
        wexcl[lane] = a - t;
    }
    __syncthreads();
    int incl = v + wexcl[wv];
    base[tid] = incl - h0;  cur[tid] = incl - h0;
    if (tid == K1_THREADS - 1) base[MAX_BINS] = incl;
    __syncthreads();

    // reserve one contiguous global run per (block, bin)
    if (tid < nbins) {
        int c = hist[tid];
        gpos[tid] = (c > 0) ? atomicAdd(&binCount[tid], c) : 0;
    }
    __syncthreads();

    // LDS scatter into bin-sorted order
#pragma unroll
    for (int k = 0; k < K1_EPT; k++) {
        if (bv[k] >= 0) {
            int p = atomicAdd(&cur[bv[k]], 1);
            srec[p] = rv[k];
        }
    }
    __syncthreads();

    // O(n) slot->bin table
    if (tid < nbins) {
        int j0 = base[tid], j1 = base[tid + 1];
        for (int j = j0; j < j1; j++) binof[j] = (unsigned short)tid;
    }
    __syncthreads();

    // copy runs out: consecutive i -> consecutive global dst within a run
    for (int i = tid; i < nvalid; i += K1_THREADS) {
        int b = binof[i];
        int off = gpos[b] + (i - base[b]);
        if (off < BINCAP)
            recs[(long)b * BINCAP + off] = srec[i];
    }
}

// ---------- K2: per-bin LDS sort + depth-3 register pipeline ----------------
// sched_barrier(0) at the end of each PREF pins its 4 row-loads BEFORE the
// following COMP in issue order -> loads stay live across ~2 COMP bodies,
// forcing true depth-3 (the compiler otherwise sinks loads to uses = depth-1,
// which matches the measured 9.4 GB/s/CU latency-bound floor).
__global__ void __launch_bounds__(K2_THREADS, 2)
aggregate_bin_kernel(const unsigned short* __restrict__ emb16,
                     const float* __restrict__ weight,
                     const unsigned* __restrict__ recs,
                     const int* __restrict__ binCount,
                     float* __restrict__ out, int n_ent) {
    __shared__ unsigned raw[BINCAP];
    __shared__ unsigned sorted[BINCAP + 16];   // +16: zeroed pad for over-reads
    __shared__ float wlds[NREL * D];           // 8KB relation-weight cache
    __shared__ float wz[D];                    // 256B zero weights (pad lanes)
    __shared__ int hist[BIN_SIZE];
    __shared__ int off[BIN_SIZE];
    __shared__ int cur[BIN_SIZE];

    int tid = threadIdx.x;
    int b = blockIdx.x;
    int n = min(binCount[b], BINCAP);

    // zero only the 16-entry pad [n, n+16) — scatter fills [0,n)
    if (tid < 16) sorted[n + tid] = 0u;
    if (tid >= 448 && tid < 448 + D) wz[tid - 448] = 0.f;
    for (int i = tid; i < NREL * D; i += K2_THREADS) wlds[i] = weight[i];
    if (tid < BIN_SIZE) hist[tid] = 0;
    __syncthreads();

    const unsigned* gr = recs + (long)b * BINCAP;
    for (int i = tid; i < n; i += K2_THREADS) {   // contiguous ~10KB read
        unsigned q = gr[i];
        raw[i] = q;
        atomicAdd(&hist[(q >> 22) & 127], 1);
    }
    __syncthreads();

    int lane = tid & 63;
    int wave = tid >> 6;

    // single-wave shfl exclusive scan of hist[128]
    if (wave == 0) {
        int h0 = hist[lane];
        int h1 = hist[64 + lane];
        int s0 = h0, s1 = h1;
#pragma unroll
        for (int s = 1; s < 64; s <<= 1) {
            int t0 = __shfl_up(s0, s);
            int t1 = __shfl_up(s1, s);
            if (lane >= s) { s0 += t0; s1 += t1; }
        }
        int tot0 = __shfl(s0, 63);
        int e0 = s0 - h0;
        int e1 = tot0 + s1 - h1;
        off[lane] = e0;      cur[lane] = e0;
        off[64 + lane] = e1; cur[64 + lane] = e1;
    }
    __syncthreads();

    for (int i = tid; i < n; i += K2_THREADS) {   // LDS scatter into sorted order
        unsigned q = raw[i];
        int p = atomicAdd(&cur[(q >> 22) & 127], 1);
        sorted[p] = q;
    }
    __syncthreads();

    int g = lane >> 4;            // edge subgroup (0..3)
    int c4 = (lane & 15) << 2;    // feature quad offset
    int hbase = b << BIN_SHIFT;

    int oA, dA, oB, dB, oC, dC;
    ushort4 ua0, ua1, ua2, ua3, ub0, ub1, ub2, ub3, uc0, uc1, uc2, uc3;
    float4 wa0, wa1, wa2, wa3, wb0, wb1, wb2, wb3, wc0, wc1, wc2, wc3;

// prefetch head J's first 16 edges. sched_barrier(0) pins the issued loads
// before all following code -> true in-flight depth.
#define K2_PREF(J, o_, d_, u0, u1, u2, u3, w0, w1, w2, w3)                    \
    do {                                                                       \
        int hh_ = wave + ((J) << 3);                                           \
        o_ = off[hh_]; d_ = hist[hh_];                                         \
        unsigned q0 = sorted[o_ + g];      unsigned q1 = sorted[o_ + 4 + g];   \
        unsigned q2 = sorted[o_ + 8 + g];  unsigned q3 = sorted[o_ + 12 + g];  \
        bool k0 = (g < d_), k1 = (4 + g < d_), k2 = (8 + g < d_),              \
             k3 = (12 + g < d_);                                               \
        q0 = k0 ? q0 : 0u;  q1 = k1 ? q1 : 0u;                                 \
        q2 = k2 ? q2 : 0u;  q3 = k3 ? q3 : 0u;                                 \
        u0 = *(const ushort4*)&emb16[((long)(q0 & 0x1FFFF) << 6) + c4];        \
        u1 = *(const ushort4*)&emb16[((long)(q1 & 0x1FFFF) << 6) + c4];        \
        u2 = *(const ushort4*)&emb16[((long)(q2 & 0x1FFFF) << 6) + c4];        \
        u3 = *(const ushort4*)&emb16[((long)(q3 & 0x1FFFF) << 6) + c4];        \
        w0 = *(const float4*)(k0 ? &wlds[(((q0 >> 17) & 31) << 6) + c4]        \
                                 : &wz[c4]);                                   \
        w1 = *(const float4*)(k1 ? &wlds[(((q1 >> 17) & 31) << 6) + c4]        \
                                 : &wz[c4]);                                   \
        w2 = *(const float4*)(k2 ? &wlds[(((q2 >> 17) & 31) << 6) + c4]        \
                                 : &wz[c4]);                                   \
        w3 = *(const float4*)(k3 ? &wlds[(((q3 >> 17) & 31) << 6) + c4]        \
                                 : &wz[c4]);                                   \
        __builtin_amdgcn_sched_barrier(0);                                     \
    } while (0)

#define K2_COMP(J, o_, d_, u0, u1, u2, u3, w0, w1, w2, w3)                    \
    do {                                                                       \
        int hh_ = wave + ((J) << 3);                                           \
        float4 acc = make_float4(0.f, 0.f, 0.f, 0.f);                          \
        acc.x += bf2f(u0.x) * w0.x; acc.y += bf2f(u0.y) * w0.y;                \
        acc.z += bf2f(u0.z) * w0.z; acc.w += bf2f(u0.w) * w0.w;                \
        acc.x += bf2f(u1.x) * w1.x; acc.y += bf2f(u1.y) * w1.y;                \
        acc.z += bf2f(u1.z) * w1.z; acc.w += bf2f(u1.w) * w1.w;                \
        acc.x += bf2f(u2.x) * w2.x; acc.y += bf2f(u2.y) * w2.y;                \
        acc.z += bf2f(u2.z) * w2.z; acc.w += bf2f(u2.w) * w2.w;                \
        acc.x += bf2f(u3.x) * w3.x; acc.y += bf2f(u3.y) * w3.y;                \
        acc.z += bf2f(u3.z) * w3.z; acc.w += bf2f(u3.w) * w3.w;                \
        for (int i_ = 16; i_ < d_; i_ += 16) {  /* rare: deg>16 tail */        \
            int e0_ = i_ + g, e1_ = i_ + 4 + g, e2_ = i_ + 8 + g,              \
                e3_ = i_ + 12 + g;                                             \
            unsigned t0 = sorted[o_ + e0_]; unsigned t1 = sorted[o_ + e1_];    \
            unsigned t2 = sorted[o_ + e2_]; unsigned t3 = sorted[o_ + e3_];    \
            bool c0 = (e0_ < d_), c1 = (e1_ < d_), c2 = (e2_ < d_),            \
                 c3 = (e3_ < d_);                                              \
            t0 = c0 ? t0 : 0u;  t1 = c1 ? t1 : 0u;                             \
            t2 = c2 ? t2 : 0u;  t3 = c3 ? t3 : 0u;                             \
            ushort4 v0 = *(const ushort4*)&emb16[((long)(t0 & 0x1FFFF) << 6) + c4]; \
            ushort4 v1 = *(const ushort4*)&emb16[((long)(t1 & 0x1FFFF) << 6) + c4]; \
            ushort4 v2 = *(const ushort4*)&emb16[((long)(t2 & 0x1FFFF) << 6) + c4]; \
            ushort4 v3 = *(const ushort4*)&emb16[((long)(t3 & 0x1FFFF) << 6) + c4]; \
            float4 x0 = *(const float4*)(c0 ? &wlds[(((t0 >> 17) & 31) << 6) + c4] \
                                            : &wz[c4]);                        \
            float4 x1 = *(const float4*)(c1 ? &wlds[(((t1 >> 17) & 31) << 6) + c4] \
                                            : &wz[c4]);                        \
            float4 x2 = *(const float4*)(c2 ? &wlds[(((t2 >> 17) & 31) << 6) + c4] \
                                            : &wz[c4]);                        \
            float4 x3 = *(const float4*)(c3 ? &wlds[(((t3 >> 17) & 31) << 6) + c4] \
                                            : &wz[c4]);                        \
            acc.x += bf2f(v0.x) * x0.x; acc.y += bf2f(v0.y) * x0.y;            \
            acc.z += bf2f(v0.z) * x0.z; acc.w += bf2f(v0.w) * x0.w;            \
            acc.x += bf2f(v1.x) * x1.x; acc.y += bf2f(v1.y) * x1.y;            \
            acc.z += bf2f(v1.z) * x1.z; acc.w += bf2f(v1.w) * x1.w;            \
            acc.x += bf2f(v2.x) * x2.x; acc.y += bf2f(v2.y) * x2.y;            \
            acc.z += bf2f(v2.z) * x2.z; acc.w += bf2f(v2.w) * x2.w;            \
            acc.x += bf2f(v3.x) * x3.x; acc.y += bf2f(v3.y) * x3.y;            \
            acc.z += bf2f(v3.z) * x3.z; acc.w += bf2f(v3.w) * x3.w;            \
        }                                                                      \
        acc.x += __shfl_xor(acc.x, 16); acc.y += __shfl_xor(acc.y, 16);        \
        acc.z += __shfl_xor(acc.z, 16); acc.w += __shfl_xor(acc.w, 16);        \
        acc.x += __shfl_xor(acc.x, 32); acc.y += __shfl_xor(acc.y, 32);        \
        acc.z += __shfl_xor(acc.z, 32); acc.w += __shfl_xor(acc.w, 32);        \
        if (g == 0 && hbase + hh_ < n_ent) {                                   \
            float inv = 1.f / fmaxf((float)d_, 1.f);                           \
            *(float4*)&out[((long)(hbase + hh_) << 6) + c4] =                  \
                make_float4(acc.x * inv, acc.y * inv, acc.z * inv, acc.w * inv);\
        }                                                                      \
    } while (0)

#define SET_A oA, dA, ua0, ua1, ua2, ua3, wa0, wa1, wa2, wa3
#define SET_B oB, dB, ub0, ub1, ub2, ub3, wb0, wb1, wb2, wb3
#define SET_C oC, dC, uc0, uc1, uc2, uc3, wc0, wc1, wc2, wc3
// indirection: macro args are counted BEFORE expansion, so pass the set
// through a wrapper that expands SET_* first, then rescans into K2_*.
#define PREF(J, S) K2_PREF(J, S)
#define COMP(J, S) K2_COMP(J, S)

    PREF(0, SET_A);
    PREF(1, SET_B);
#pragma unroll 1
    for (int r = 0; r < 5; ++r) {
        int j = 3 * r;
        PREF(j + 2, SET_C);
        COMP(j, SET_A);
        int ja = (j + 3 > 15) ? 15 : (j + 3);
        PREF(ja, SET_A);
        COMP(j + 1, SET_B);
        int jb = (j + 4 > 15) ? 15 : (j + 4);
        PREF(jb, SET_B);
        COMP(j + 2, SET_C);
    }
    COMP(15, SET_A);
#undef PREF
#undef COMP
#undef K2_PREF
#undef K2_COMP
#undef SET_A
#undef SET_B
#undef SET_C
}

// ---------- Fallback (R1 atomic version) for out-of-envelope shapes ----------
__global__ void fb_scatter(const float* __restrict__ emb, const int* __restrict__ head,
                           const int* __restrict__ tail, const int* __restrict__ etype,
                           const float* __restrict__ weight, float* __restrict__ out,
                           float* __restrict__ cnt, int n_edges) {
    int gtid = blockIdx.x * blockDim.x + threadIdx.x;
    int e = gtid >> 6, lane = threadIdx.x & 63;
    if (e >= n_edges) return;
    int h = head[e], t = tail[e], r = etype[e];
    atomicAdd(&out[(long)h * D + lane], emb[(long)t * D + lane] * weight[r * D + lane]);
    if (lane == 0) atomicAdd(&cnt[h], 1.0f);
}
__global__ void fb_divide(float* __restrict__ out, const float* __restrict__ cnt, int n) {
    int i = blockIdx.x * blockDim.x + threadIdx.x;
    if (i < n) out[i] = out[i] / fmaxf(cnt[i >> 6], 1.0f);
}

// ===========================================================================

extern "C" void kernel_launch(void* const* d_in, const int* in_sizes, int n_in,
                              void* d_out, int out_size, void* d_ws, size_t ws_size,
                              hipStream_t stream) {
    const float* emb    = (const float*)d_in[0];  // [N_ENT, 64] fp32
    const int*   eidx   = (const int*)  d_in[1];  // [2, E] int32
    const int*   etype  = (const int*)  d_in[2];  // [E] int32
    const float* weight = (const float*)d_in[3];  // [32, 64] fp32
    float* out = (float*)d_out;

    int n_edges = in_sizes[2];
    int n_ent   = out_size / D;
    const int* head = eidx;
    const int* tail = eidx + n_edges;

    int nbins = (n_ent + BIN_SIZE - 1) >> BIN_SHIFT;           // 782 for 100k
    size_t recs_bytes = sizeof(int) * ((size_t)nbins * BINCAP);
    size_t cnt_bytes  = sizeof(int) * (size_t)nbins;
    size_t emb16_off  = (cnt_bytes + recs_bytes + 15) & ~((size_t)15);
    size_t need = emb16_off + (size_t)n_ent * D * sizeof(unsigned short);
    long mean_load = (n_ent > 0) ? ((long)n_edges * BIN_SIZE / n_ent) : 0;   // 1600
    bool ok = (n_ent <= 131072) && (nbins <= MAX_BINS) && (ws_size >= need) &&
              (mean_load + 700 <= BINCAP);

    if (ok) {
        int* binCount  = (int*)d_ws;                     // [nbins]
        unsigned* recs = (unsigned*)(binCount + nbins);  // [nbins * BINCAP]
        unsigned short* emb16 = (unsigned short*)((char*)d_ws + emb16_off);

        long n4 = (long)n_ent * D / 4;                   // float4 count (D=64 -> exact)
        int nsort = (n_edges + K1_EPB - 1) / K1_EPB;     // 245 for 1.25M
        int ncvt  = (int)((n4 + K1_THREADS - 1) / K1_THREADS);

        (void)hipMemsetAsync(binCount, 0, (size_t)nbins * sizeof(int), stream);
        prep_kernel<<<nsort + ncvt, K1_THREADS, 0, stream>>>(
            emb, emb16, head, tail, etype, binCount, recs,
            nbins, n_edges, n4, nsort);

        aggregate_bin_kernel<<<nbins, K2_THREADS, 0, stream>>>(
            emb16, weight, recs, binCount, out, n_ent);
    } else {
        float* cnt = (float*)d_ws;
        (void)hipMemsetAsync(out, 0, (size_t)out_size * sizeof(float), stream);
        (void)hipMemsetAsync(cnt, 0, (size_t)n_ent * sizeof(float), stream);
        long tt = (long)n_edges * 64;
        fb_scatter<<<(int)((tt + 255) / 256), 256, 0, stream>>>(
            emb, head, tail, etype, weight, out, cnt, n_edges);
        fb_divide<<<(out_size + 255) / 256, 256, 0, stream>>>(out, cnt, out_size);
    }
}